// Round 35
// baseline (117.911 us; speedup 1.0000x reference)
//
#include <hip/hip_runtime.h>
#include <hip/hip_bf16.h>

typedef __bf16 bf16x8 __attribute__((ext_vector_type(8)));
typedef __bf16 bf16x4 __attribute__((ext_vector_type(4)));
typedef float  f32x4  __attribute__((ext_vector_type(4)));
typedef float  f32x16 __attribute__((ext_vector_type(16)));

#define V_TOTAL 32768
#define NT      640        // 10 waves: 0-7 consumers (L2/L3), 8-9 producers (L1/out)
#define NV      32         // v-chunks of 64 positions per block
#define NBLK    256        // 1 block/CU; 16 blocks per sample

#define W2_LDS  65536      // ks 0..7 panels (ks 8..15 in consumer registers)
#define H1_LDS  65536      // h1[2] dbuf: 2 x 32KB, chunk (K*2+nt)*1KB lane-linear
#define RED_LDS 4096       // red[2][512]
#define LDS_TOT (W2_LDS + H1_LDS + RED_LDS)   // 135168 < 160 KiB

// async global->LDS, 16B/lane; LDS dest = wave-uniform base (+lane*16 by HW)
#define GLOAD_LDS16(g, l) __builtin_amdgcn_global_load_lds( \
    (const __attribute__((address_space(1))) void*)(g),     \
    (__attribute__((address_space(3))) void*)(l), 16, 0, 0)

// ---- prep: w2 fp32 -> bf16 in 32x32x16 A-frag chunk order ----
// chunk c = ks*8 + tile (1KB each): lane l, elem j -> W2[tile*32+(l&31)][ks*16+(l>>5)*8+j]
__global__ void w2_to_bf16(const float* __restrict__ w2, __bf16* __restrict__ w2b) {
    int i = blockIdx.x * 256 + threadIdx.x;   // 8*256*256 total
    int e = i >> 16, q = i & 65535;
    int c = q >> 9, w = q & 511, lane = w >> 3, j = w & 7;
    int ks = c >> 3, tile = c & 7;
    int m = tile * 32 + (lane & 31);
    int k = ks * 16 + (lane >> 5) * 8 + j;
    w2b[i] = (__bf16)w2[e * 65536 + m * 256 + k];
}

__global__ __launch_bounds__(NT) void fused_mlp(
    const float* __restrict__ x,  const int* __restrict__ obj,
    const float* __restrict__ w1, const float* __restrict__ b1,
    const float* __restrict__ b2, const float* __restrict__ w3,
    const float* __restrict__ b3, const __bf16* __restrict__ w2b,
    float* __restrict__ out)
{
    extern __shared__ __align__(16) char smem[];
    char*  w2s = smem;                      // ks 0..7: chunk (ks*8+tile)*1024, lane-linear
    char*  h1t = smem + W2_LDS;             // [2 panels][(K*2+nt)*1024]
    float* red = (float*)(smem + W2_LDS + H1_LDS);   // [2][512]

    const int t    = threadIdx.x;
    const int lane = t & 63;
    const int wv   = t >> 6;                // 0..9
    const int c32  = lane & 31;
    const int hh   = lane >> 5;
    const int b    = blockIdx.x >> 4;       // sample (16 blocks each)
    const int g    = blockIdx.x & 15;
    const int e    = __builtin_amdgcn_readfirstlane(obj[b]);
    const __bf16* w2sw = w2b + (size_t)e * 65536;   // pre-swizzled chunk order
    const int p    = wv - 8;                // producer id 0/1 (consumers: unused)

    // ---- stage ks 0..7 of W2[e] (64 KB) by the 8 consumer waves ----
    if (wv < 8) {
        #pragma unroll
        for (int it = 0; it < 8; ++it) {
            int c0 = it * 8 + wv;           // chunk id, wave-uniform
            GLOAD_LDS16(w2sw + c0 * 512 + lane * 8, w2s + c0 * 1024);
        }
    }

    const float* w1e = w1 + e * 1536;
    const float* b1e = b1 + e * 256;
    const float* b2e = b2 + e * 256;
    const float* w3e = w3 + e * 256;
    const float  b3e = b3[e];
    const float* xe = x + (size_t)b * 6 * V_TOTAL;

    // ---- consumer persistent state: ks 8..15 A-frags (32 VGPRs) ----
    bf16x8 aar[8];
    if (wv < 8)
        #pragma unroll
        for (int k2 = 0; k2 < 8; ++k2)
            aar[k2] = *(const bf16x8*)(w2sw + ((8 + k2) * 8 + wv) * 512 + lane * 8);

    // ---- producer: L1 for all 8 tiles, position half p; state rebuilt per chunk ----
    auto produce = [&](int icb, int pan) {
        bf16x8 xfp = {};
        #pragma unroll
        for (int i = 0; i < 6; ++i)
            xfp[i] = (__bf16)xe[i * V_TOTAL + (g * NV + icb) * 64 + p * 32 + c32];
        #pragma unroll
        for (int tile = 0; tile < 8; ++tile) {
            bf16x8 a1 = {};                 // W1 frag (L1$-hot reload; producers have slack)
            if (hh == 0)
                #pragma unroll
                for (int j = 0; j < 6; ++j)
                    a1[j] = (__bf16)w1e[(tile * 32 + c32) * 6 + j];
            f32x16 b1f;
            #pragma unroll
            for (int gg = 0; gg < 4; ++gg) {
                f32x4 v = *(const f32x4*)(b1e + tile * 32 + gg * 8 + hh * 4);
                #pragma unroll
                for (int q = 0; q < 4; ++q) b1f[gg * 4 + q] = v[q];
            }
            f32x16 h = __builtin_amdgcn_mfma_f32_32x32x16_bf16(a1, xfp, b1f, 0, 0, 0);
            #pragma unroll
            for (int gg = 0; gg < 4; ++gg) {
                bf16x4 pk;
                #pragma unroll
                for (int q = 0; q < 4; ++q) pk[q] = (__bf16)fmaxf(h[gg * 4 + q], 0.f);
                // m = tile*32 + q+8*gg+4*hh -> chunk K=tile*2+(gg>>1), nt=p
                *(bf16x4*)(h1t + pan * 32768 + ((tile * 2 + (gg >> 1)) * 2 + p) * 1024
                           + (gg & 1) * 512 + c32 * 16 + hh * 8) = pk;
            }
        }
    };

    if (wv >= 8) produce(0, 0);             // prologue: chunk 0 -> panel 0

    for (int iv = 0; iv < NV; ++iv) {
        __syncthreads();   // panel iv&1 ready; red[(iv-1)&1] ready; (iv==0: staging drained)

        if (wv < 8) {
            // ---- consumer: 32 MFMA; ks 0..7 A from LDS, ks 8..15 from regs ----
            f32x16 acc0, acc1;
            #pragma unroll
            for (int gg = 0; gg < 4; ++gg) {
                f32x4 v = *(const f32x4*)(b2e + wv * 32 + gg * 8 + hh * 4);
                #pragma unroll
                for (int q = 0; q < 4; ++q) { acc0[gg*4+q] = v[q]; acc1[gg*4+q] = v[q]; }
            }
            const char* bbase = h1t + (iv & 1) * 32768 + lane * 16;
            #pragma unroll
            for (int ks = 0; ks < 8; ++ks) {
                const bf16x8 aw  = *(const bf16x8*)(w2s + (ks * 8 + wv) * 1024 + lane * 16);
                const bf16x8 bb0 = *(const bf16x8*)(bbase + (ks * 2 + 0) * 1024);
                const bf16x8 bb1 = *(const bf16x8*)(bbase + (ks * 2 + 1) * 1024);
                acc0 = __builtin_amdgcn_mfma_f32_32x32x16_bf16(aw, bb0, acc0, 0, 0, 0);
                acc1 = __builtin_amdgcn_mfma_f32_32x32x16_bf16(aw, bb1, acc1, 0, 0, 0);
            }
            #pragma unroll
            for (int k2 = 0; k2 < 8; ++k2) {
                const bf16x8 bb0 = *(const bf16x8*)(bbase + ((8 + k2) * 2 + 0) * 1024);
                const bf16x8 bb1 = *(const bf16x8*)(bbase + ((8 + k2) * 2 + 1) * 1024);
                acc0 = __builtin_amdgcn_mfma_f32_32x32x16_bf16(aar[k2], bb0, acc0, 0, 0, 0);
                acc1 = __builtin_amdgcn_mfma_f32_32x32x16_bf16(aar[k2], bb1, acc1, 0, 0, 0);
            }
            // ---- L3 partials into red[iv&1] ----
            float p0 = 0.f, p1 = 0.f;
            #pragma unroll
            for (int gg = 0; gg < 4; ++gg) {
                f32x4 wq = *(const f32x4*)(w3e + wv * 32 + gg * 8 + hh * 4);
                #pragma unroll
                for (int q = 0; q < 4; ++q) {
                    p0 = fmaf(wq[q], fmaxf(acc0[gg * 4 + q], 0.f), p0);
                    p1 = fmaf(wq[q], fmaxf(acc1[gg * 4 + q], 0.f), p1);
                }
            }
            p0 += __shfl_xor(p0, 32, 64);
            p1 += __shfl_xor(p1, 32, 64);
            float* rp = red + (iv & 1) * 512;
            if (lane < 32) {
                rp[wv * 64 + c32]      = p0;
                rp[wv * 64 + 32 + c32] = p1;
            }
        } else {
            // ---- producer: out-write(iv-1), then L1(iv+1) into other panel ----
            if (p == 0 && iv > 0) {
                const float* rq = red + ((iv - 1) & 1) * 512;
                float s = b3e;
                #pragma unroll
                for (int w8 = 0; w8 < 8; ++w8) s += rq[w8 * 64 + lane];
                out[(size_t)b * V_TOTAL + (g * NV + iv - 1) * 64 + lane] = s;
            }
            if (iv + 1 < NV) produce(iv + 1, (iv + 1) & 1);
        }
    }
    __syncthreads();   // red[(NV-1)&1] ready
    if (wv == 8) {
        const float* rq = red + ((NV - 1) & 1) * 512;
        float s = b3e;
        #pragma unroll
        for (int w8 = 0; w8 < 8; ++w8) s += rq[w8 * 64 + lane];
        out[(size_t)b * V_TOTAL + (g * NV + NV - 1) * 64 + lane] = s;
    }
}

extern "C" void kernel_launch(void* const* d_in, const int* in_sizes, int n_in,
                              void* d_out, int out_size, void* d_ws, size_t ws_size,
                              hipStream_t stream) {
    const float* x   = (const float*)d_in[0];
    const int*   obj = (const int*)d_in[1];
    const float* w1  = (const float*)d_in[2];
    const float* b1  = (const float*)d_in[3];
    const float* w2  = (const float*)d_in[4];
    const float* b2  = (const float*)d_in[5];
    const float* w3  = (const float*)d_in[6];
    const float* b3  = (const float*)d_in[7];
    float*  out = (float*)d_out;
    __bf16* w2b = (__bf16*)d_ws;   // 8*256*256 bf16 = 1 MB, 32x32-frag chunk order

    (void)hipFuncSetAttribute((const void*)fused_mlp,
                              hipFuncAttributeMaxDynamicSharedMemorySize, LDS_TOT);

    w2_to_bf16<<<2048, 256, 0, stream>>>(w2, w2b);
    fused_mlp<<<NBLK, NT, LDS_TOT, stream>>>(x, obj, w1, b1, b2, w3, b3, w2b, out);
}

// Round 36
// 74.302 us; speedup vs baseline: 1.5869x; 1.5869x over previous
//
#include <hip/hip_runtime.h>
#include <hip/hip_bf16.h>

typedef __bf16 bf16x8 __attribute__((ext_vector_type(8)));
typedef __bf16 bf16x4 __attribute__((ext_vector_type(4)));
typedef float  f32x4  __attribute__((ext_vector_type(4)));
typedef float  f32x16 __attribute__((ext_vector_type(16)));

#define V_TOTAL 32768
#define NT      512        // 8 waves; wave owns one 32-row m-tile (tile = wv)
#define NV      32         // v-chunks of 64 positions per block
#define NBLK    256        // 1 block/CU; 16 blocks per sample

// LDS: h1 32KB + red 2KB only (static). W2 entirely in registers (aar[16] = 64 VGPRs).
// Session ledger: best = this structure @ 74.4 us (R34). All parallelism levers
// (occupancy, reg-budget, big blocks, wave-specialization) measured dead on this
// toolchain; ds_read->MFMA latency at 2 waves/SIMD is the residual.

// ---- prep: w2 fp32 -> bf16 in 32x32x16 A-frag chunk order ----
// chunk c = ks*8 + tile (1KB each): lane l, elem j -> W2[tile*32+(l&31)][ks*16+(l>>5)*8+j]
__global__ void w2_to_bf16(const float* __restrict__ w2, __bf16* __restrict__ w2b) {
    int i = blockIdx.x * 256 + threadIdx.x;   // 8*256*256 total
    int e = i >> 16, q = i & 65535;
    int c = q >> 9, w = q & 511, lane = w >> 3, j = w & 7;
    int ks = c >> 3, tile = c & 7;
    int m = tile * 32 + (lane & 31);
    int k = ks * 16 + (lane >> 5) * 8 + j;
    w2b[i] = (__bf16)w2[e * 65536 + m * 256 + k];
}

__global__ __launch_bounds__(NT) void fused_mlp(
    const float* __restrict__ x,  const int* __restrict__ obj,
    const float* __restrict__ w1, const float* __restrict__ b1,
    const float* __restrict__ b2, const float* __restrict__ w3,
    const float* __restrict__ b3, const __bf16* __restrict__ w2b,
    float* __restrict__ out)
{
    __shared__ __align__(16) char h1t[32768];   // chunk (ks*2+nt)*1KB, lane-linear B-frags
    __shared__ float red[512];

    const int t    = threadIdx.x;
    const int lane = t & 63;
    const int wv   = t >> 6;                // m-tile: rows [wv*32, wv*32+32)
    const int c32  = lane & 31;
    const int hh   = lane >> 5;
    const int b    = blockIdx.x >> 4;       // sample (16 blocks each)
    const int g    = blockIdx.x & 15;
    const int e    = __builtin_amdgcn_readfirstlane(obj[b]);
    const __bf16* w2sw = w2b + (size_t)e * 65536;   // pre-swizzled chunk order

    // ---- ALL 16 ks A-frags in registers (64 VGPRs): zero A ds_reads in-loop ----
    bf16x8 aar[16];
    #pragma unroll
    for (int ks = 0; ks < 16; ++ks)
        aar[ks] = *(const bf16x8*)(w2sw + (ks * 8 + wv) * 512 + lane * 8);

    // ---- L1 A-frag: W1[wv*32+c32][k'=hh*8+j], zero for hh==1 or j>=6 ----
    const float* w1e = w1 + e * 1536;
    const float* b1e = b1 + e * 256;
    const float* b2e = b2 + e * 256;
    const float* w3e = w3 + e * 256;
    bf16x8 aa1 = {};
    if (hh == 0)
        #pragma unroll
        for (int j = 0; j < 6; ++j) aa1[j] = (__bf16)w1e[(wv * 32 + c32) * 6 + j];
    const float b3e = b3[e];
    const float* xe = x + (size_t)b * 6 * V_TOTAL;

    bf16x8 xf[2];
    auto load_x = [&](int ic) {             // B-frag: x[k'][pos]; k'>=6 junk killed by A=0
        #pragma unroll
        for (int pt = 0; pt < 2; ++pt) {
            bf16x8 v = {};
            #pragma unroll
            for (int i = 0; i < 6; ++i)
                v[i] = (__bf16)xe[i * V_TOTAL + (g * NV + ic) * 64 + pt * 32 + c32];
            xf[pt] = v;
        }
    };
    auto do_l1 = [&]() {                    // h1 = relu(W1 x + b1): 2 MFMA 32x32x16
        f32x16 b1f;
        #pragma unroll
        for (int gg = 0; gg < 4; ++gg) {    // C row = q + 8*gg + 4*hh
            f32x4 v = *(const f32x4*)(b1e + wv * 32 + gg * 8 + hh * 4);
            #pragma unroll
            for (int q = 0; q < 4; ++q) b1f[gg * 4 + q] = v[q];
        }
        #pragma unroll
        for (int pt = 0; pt < 2; ++pt) {
            f32x16 h = __builtin_amdgcn_mfma_f32_32x32x16_bf16(aa1, xf[pt], b1f, 0, 0, 0);
            #pragma unroll
            for (int gg = 0; gg < 4; ++gg) {
                bf16x4 pk;
                #pragma unroll
                for (int q = 0; q < 4; ++q) pk[q] = (__bf16)fmaxf(h[gg * 4 + q], 0.f);
                // m = wv*32 + q+8*gg+4*hh -> chunk ks=wv*2+(gg>>1), h'=gg&1, j'=q+4*hh
                *(bf16x4*)(h1t + ((wv * 2 + (gg >> 1)) * 2 + pt) * 1024
                           + (gg & 1) * 512 + c32 * 16 + hh * 8) = pk;
            }
        }
    };

    load_x(0);

    for (int iv = 0; iv < NV; ++iv) {
        do_l1();
        if (iv + 1 < NV) load_x(iv + 1);
        __syncthreads();   // bar1: h1 ready

        // ---- layer 2: 32 MFMA 32x32x16/wave, A all-registers, B prefetch-pipelined ----
        f32x16 acc0, acc1;
        #pragma unroll
        for (int gg = 0; gg < 4; ++gg) {
            f32x4 v = *(const f32x4*)(b2e + wv * 32 + gg * 8 + hh * 4);
            #pragma unroll
            for (int q = 0; q < 4; ++q) { acc0[gg * 4 + q] = v[q]; acc1[gg * 4 + q] = v[q]; }
        }
        const char* bbase = h1t + lane * 16;
        bf16x8 nb0 = *(const bf16x8*)(bbase + 0);      // ks=0 B-frags
        bf16x8 nb1 = *(const bf16x8*)(bbase + 1024);
        #pragma unroll
        for (int ks = 0; ks < 16; ++ks) {
            const bf16x8 bb0 = nb0, bb1 = nb1;
            if (ks < 15) {                  // prefetch ks+1 under this ks's MFMA pair
                nb0 = *(const bf16x8*)(bbase + ((ks + 1) * 2 + 0) * 1024);
                nb1 = *(const bf16x8*)(bbase + ((ks + 1) * 2 + 1) * 1024);
            }
            acc0 = __builtin_amdgcn_mfma_f32_32x32x16_bf16(aar[ks], bb0, acc0, 0, 0, 0);
            acc1 = __builtin_amdgcn_mfma_f32_32x32x16_bf16(aar[ks], bb1, acc1, 0, 0, 0);
        }

        // ---- layer 3: s[col] = sum_m w3[m]*relu(h2[m][col]) ----
        float p0 = 0.f, p1 = 0.f;
        #pragma unroll
        for (int gg = 0; gg < 4; ++gg) {
            f32x4 wq = *(const f32x4*)(w3e + wv * 32 + gg * 8 + hh * 4);
            #pragma unroll
            for (int q = 0; q < 4; ++q) {
                p0 = fmaf(wq[q], fmaxf(acc0[gg * 4 + q], 0.f), p0);
                p1 = fmaf(wq[q], fmaxf(acc1[gg * 4 + q], 0.f), p1);
            }
        }
        p0 += __shfl_xor(p0, 32, 64);       // combine lane halves (row sets differ by 4*hh)
        p1 += __shfl_xor(p1, 32, 64);
        if (lane < 32) {
            red[wv * 64 + c32]      = p0;
            red[wv * 64 + 32 + c32] = p1;
        }
        __syncthreads();   // bar2: red ready; h1 reads done (next L1 may overwrite)

        if (t < 64) {      // red re-written only after next bar1 -> safe
            float s = b3e;
            #pragma unroll
            for (int w8 = 0; w8 < 8; ++w8) s += red[w8 * 64 + t];
            out[(size_t)b * V_TOTAL + (g * NV + iv) * 64 + t] = s;
        }
    }
}

extern "C" void kernel_launch(void* const* d_in, const int* in_sizes, int n_in,
                              void* d_out, int out_size, void* d_ws, size_t ws_size,
                              hipStream_t stream) {
    const float* x   = (const float*)d_in[0];
    const int*   obj = (const int*)d_in[1];
    const float* w1  = (const float*)d_in[2];
    const float* b1  = (const float*)d_in[3];
    const float* w2  = (const float*)d_in[4];
    const float* b2  = (const float*)d_in[5];
    const float* w3  = (const float*)d_in[6];
    const float* b3  = (const float*)d_in[7];
    float*  out = (float*)d_out;
    __bf16* w2b = (__bf16*)d_ws;   // 8*256*256 bf16 = 1 MB, 32x32-frag chunk order

    w2_to_bf16<<<2048, 256, 0, stream>>>(w2, w2b);
    fused_mlp<<<NBLK, NT, 0, stream>>>(x, obj, w1, b1, b2, w3, b3, w2b, out);
}